// Round 14
// baseline (307.664 us; speedup 1.0000x reference)
//
#include <hip/hip_runtime.h>
#include <stdint.h>

// Problem constants
#define BB    8
#define HH    16
#define SS    640
#define STOK  512
#define STMN  128
#define HD    64
#define DIM   1024
#define NEGINF (-1e18f)

typedef short v8s __attribute__((ext_vector_type(8)));
typedef float v4f __attribute__((ext_vector_type(4)));

static __device__ __forceinline__ ushort f2b(float f) {
    union { float f; uint32_t u; } x; x.f = f;
    uint32_t u = (x.u + 0x7FFFu + ((x.u >> 16) & 1u)) >> 16;
    return (ushort)u;
}
static __device__ __forceinline__ float b2f(ushort h) {
    union { uint32_t u; float f; } x; x.u = ((uint32_t)h) << 16;
    return x.f;
}

// async global->LDS, 16 B per lane; dest is wave-uniform base + lane*16
static __device__ __forceinline__ void gld16(const ushort* g, ushort* l) {
    __builtin_amdgcn_global_load_lds(
        (const __attribute__((address_space(1))) unsigned int*)g,
        (__attribute__((address_space(3))) unsigned int*)l, 16, 0, 0);
}

// ---------------------------------------------------------------------------
// Kernel A0: convert x (stok||stm, [5120][1024]) and qkv_w ([3072][1024]) to
// bf16; split out_w ([1024][1024]) into bf16 hi/lo pair.  Pure streaming.
// ---------------------------------------------------------------------------
__global__ __launch_bounds__(256) void cvt_bf16(
    const float* __restrict__ stok, const float* __restrict__ stm,
    const float* __restrict__ W, const float* __restrict__ Wo,
    ushort* __restrict__ xb, ushort* __restrict__ Wb,
    ushort* __restrict__ Woh, ushort* __restrict__ Wol)
{
    const int i = blockIdx.x * 256 + threadIdx.x;
    const int XG = 5120 * 256;                      // float4-groups in x
    const int WG = 3072 * 256;                      // float4-groups in qkv_w
    if (i < XG + WG) {
        float4 v; ushort* dst;
        if (i < XG) {
            int row = i >> 8, g = i & 255;
            int b = row / SS, s = row % SS;
            const float* src = (s < STOK)
                ? stok + ((size_t)b * STOK + s) * DIM
                : stm  + ((size_t)b * STMN + (s - STOK)) * DIM;
            v = *reinterpret_cast<const float4*>(src + g * 4);
            dst = xb + (size_t)row * DIM + g * 4;
        } else {
            int j = i - XG;
            int row = j >> 8, g = j & 255;
            v = *reinterpret_cast<const float4*>(W + (size_t)row * DIM + g * 4);
            dst = Wb + (size_t)row * DIM + g * 4;
        }
        ushort4 o;
        o.x = f2b(v.x); o.y = f2b(v.y); o.z = f2b(v.z); o.w = f2b(v.w);
        *reinterpret_cast<ushort4*>(dst) = o;
    } else {
        int j = i - XG - WG;
        int row = j >> 8, g = j & 255;
        float4 v = *reinterpret_cast<const float4*>(Wo + (size_t)row * DIM + g * 4);
        ushort4 hi, lo;
        hi.x = f2b(v.x); lo.x = f2b(v.x - b2f(hi.x));
        hi.y = f2b(v.y); lo.y = f2b(v.y - b2f(hi.y));
        hi.z = f2b(v.z); lo.z = f2b(v.z - b2f(hi.z));
        hi.w = f2b(v.w); lo.w = f2b(v.w - b2f(hi.w));
        *reinterpret_cast<ushort4*>(&Woh[(size_t)row * DIM + g * 4]) = hi;
        *reinterpret_cast<ushort4*>(&Wol[(size_t)row * DIM + g * 4]) = lo;
    }
}

// ---------------------------------------------------------------------------
// Kernel A: QKV projection, m97-style LDS-staged MFMA GEMM (unchanged r13).
// ---------------------------------------------------------------------------
__global__ __launch_bounds__(256) void gemm_qkv_mfma(
    const ushort* __restrict__ xb, const ushort* __restrict__ Wb,
    const float* __restrict__ bias,
    ushort* __restrict__ qb, ushort* __restrict__ kb, ushort* __restrict__ vtb)
{
    __shared__ __align__(16) ushort As[64 * 32];     // 4 KB
    __shared__ __align__(16) ushort Bs[128 * 32];    // 8 KB
    const int t = threadIdx.x, lane = t & 63, w = t >> 6;
    const int swz = ((blockIdx.x & 7) * 240) + (blockIdx.x >> 3);
    const int nt = swz / 80, mt = swz % 80;
    const int mb = mt * 64, nb = nt * 128;
    const int wm = (w >> 1) * 32, wn = (w & 1) * 64;
    const int lg = lane >> 4, lc = lane & 15;

    const int ra = t >> 2, pa = t & 3;
    const ushort* gA = xb + (size_t)(mb + ra) * DIM + (pa ^ ((ra >> 1) & 3)) * 8;
    ushort* lA = As + (w * 64) * 8;
    const ushort* gB[2]; ushort* lB[2];
#pragma unroll
    for (int i = 0; i < 2; ++i) {
        int c = t + i * 256, rb = c >> 2, pb = c & 3;
        gB[i] = Wb + (size_t)(nb + rb) * DIM + (pb ^ ((rb >> 1) & 3)) * 8;
        lB[i] = Bs + (i * 256 + w * 64) * 8;
    }

    v4f acc[2][4];
#pragma unroll
    for (int i = 0; i < 2; ++i)
#pragma unroll
        for (int j = 0; j < 4; ++j) acc[i][j] = (v4f){0.f, 0.f, 0.f, 0.f};

    for (int kt = 0; kt < 32; ++kt) {
        const int ko = kt * 32;
        __syncthreads();
        gld16(gA + ko, lA);
        gld16(gB[0] + ko, lB[0]);
        gld16(gB[1] + ko, lB[1]);
        __syncthreads();
        v8s af[2], bf[4];
#pragma unroll
        for (int i = 0; i < 2; ++i) {
            int ar = wm + i * 16 + lc;
            af[i] = *reinterpret_cast<const v8s*>(&As[ar * 32 + (lg ^ ((ar >> 1) & 3)) * 8]);
        }
#pragma unroll
        for (int j = 0; j < 4; ++j) {
            int br = wn + j * 16 + lc;
            bf[j] = *reinterpret_cast<const v8s*>(&Bs[br * 32 + (lg ^ ((br >> 1) & 3)) * 8]);
        }
#pragma unroll
        for (int i = 0; i < 2; ++i)
#pragma unroll
            for (int j = 0; j < 4; ++j)
                acc[i][j] = __builtin_amdgcn_mfma_f32_16x16x32_bf16(af[i], bf[j], acc[i][j], 0, 0, 0);
    }

    const int nregion = nb >> 10;                  // 0=q 1=k 2=v
    if (nregion < 2) {
        ushort* dst = nregion ? kb : qb;
        const float scale = nregion ? 1.0f : 0.125f;
#pragma unroll
        for (int j = 0; j < 4; ++j) {
            int n = nb + wn + j * 16 + lc;
            int nn = n & 1023, h = nn >> 6, d = nn & 63;
            float bi = bias[n];
#pragma unroll
            for (int i = 0; i < 2; ++i) {
                int m0 = mb + wm + i * 16 + lg * 4;
                int b = m0 / SS, s0 = m0 % SS;
                size_t base = (((size_t)b * HH + h) * SS + s0) * HD + d;
#pragma unroll
                for (int r = 0; r < 4; ++r)
                    dst[base + (size_t)r * HD] = f2b((acc[i][j][r] + bi) * scale);
            }
        }
    } else {
#pragma unroll
        for (int j = 0; j < 4; ++j) {
            int n = nb + wn + j * 16 + lc;
            int nn = n & 1023, h = nn >> 6, d = nn & 63;
            float bi = bias[n];
#pragma unroll
            for (int i = 0; i < 2; ++i) {
                int m0 = mb + wm + i * 16 + lg * 4;   // 4 consecutive s, same b
                int b = m0 / SS, s0 = m0 % SS;
                ushort4 pk;
                pk.x = f2b(acc[i][j][0] + bi);
                pk.y = f2b(acc[i][j][1] + bi);
                pk.z = f2b(acc[i][j][2] + bi);
                pk.w = f2b(acc[i][j][3] + bi);
                *reinterpret_cast<ushort4*>(
                    &vtb[(((size_t)b * HH + h) * HD + d) * SS + s0]) = pk;
            }
        }
    }
}

// ---------------------------------------------------------------------------
// Kernel C: out projection, LDS-staged double-bf16 MFMA GEMM (unchanged r13).
// ---------------------------------------------------------------------------
__global__ __launch_bounds__(256) void gemm_out_mfma(
    const ushort* __restrict__ Xh, const ushort* __restrict__ Xl,
    const ushort* __restrict__ Wh, const ushort* __restrict__ Wl,
    const float* __restrict__ bias, float* __restrict__ out)
{
    __shared__ __align__(16) ushort Ah[64 * 32];
    __shared__ __align__(16) ushort Al[64 * 32];
    __shared__ __align__(16) ushort Bh[64 * 32];
    __shared__ __align__(16) ushort Bl[64 * 32];
    const int t = threadIdx.x, lane = t & 63, w = t >> 6;
    const int swz = ((blockIdx.x & 7) * 160) + (blockIdx.x >> 3);
    const int nt = swz / 80, mt = swz % 80;
    const int mb = mt * 64, nb = nt * 64;
    const int wm = (w >> 1) * 32, wn = (w & 1) * 32;
    const int lg = lane >> 4, lc = lane & 15;

    const int rr = t >> 2, pp = t & 3;
    const size_t goff = (size_t)rr * DIM + (pp ^ ((rr >> 1) & 3)) * 8;
    const ushort* gAh = Xh + (size_t)mb * DIM + goff;
    const ushort* gAl = Xl + (size_t)mb * DIM + goff;
    const ushort* gBh = Wh + (size_t)nb * DIM + goff;
    const ushort* gBl = Wl + (size_t)nb * DIM + goff;
    const int wchunk = (w * 64) * 8;

    v4f acc[2][2];
#pragma unroll
    for (int i = 0; i < 2; ++i)
#pragma unroll
        for (int j = 0; j < 2; ++j) acc[i][j] = (v4f){0.f, 0.f, 0.f, 0.f};

    for (int kt = 0; kt < 32; ++kt) {
        const int ko = kt * 32;
        __syncthreads();
        gld16(gAh + ko, Ah + wchunk);
        gld16(gAl + ko, Al + wchunk);
        gld16(gBh + ko, Bh + wchunk);
        gld16(gBl + ko, Bl + wchunk);
        __syncthreads();
        v8s ahf[2], alf[2], bhf[2], blf[2];
#pragma unroll
        for (int i = 0; i < 2; ++i) {
            int ar = wm + i * 16 + lc;
            int ao = ar * 32 + (lg ^ ((ar >> 1) & 3)) * 8;
            ahf[i] = *reinterpret_cast<const v8s*>(&Ah[ao]);
            alf[i] = *reinterpret_cast<const v8s*>(&Al[ao]);
            int br = wn + i * 16 + lc;
            int bo = br * 32 + (lg ^ ((br >> 1) & 3)) * 8;
            bhf[i] = *reinterpret_cast<const v8s*>(&Bh[bo]);
            blf[i] = *reinterpret_cast<const v8s*>(&Bl[bo]);
        }
#pragma unroll
        for (int i = 0; i < 2; ++i)
#pragma unroll
            for (int j = 0; j < 2; ++j)
                acc[i][j] = __builtin_amdgcn_mfma_f32_16x16x32_bf16(ahf[i], bhf[j], acc[i][j], 0, 0, 0);
#pragma unroll
        for (int i = 0; i < 2; ++i)
#pragma unroll
            for (int j = 0; j < 2; ++j)
                acc[i][j] = __builtin_amdgcn_mfma_f32_16x16x32_bf16(alf[i], bhf[j], acc[i][j], 0, 0, 0);
#pragma unroll
        for (int i = 0; i < 2; ++i)
#pragma unroll
            for (int j = 0; j < 2; ++j)
                acc[i][j] = __builtin_amdgcn_mfma_f32_16x16x32_bf16(ahf[i], blf[j], acc[i][j], 0, 0, 0);
    }

#pragma unroll
    for (int j = 0; j < 2; ++j) {
        int n = nb + wn + j * 16 + lc;
        float bi = bias[n];
#pragma unroll
        for (int i = 0; i < 2; ++i) {
            int m0 = mb + wm + i * 16 + lg * 4;
#pragma unroll
            for (int r = 0; r < 4; ++r)
                out[(size_t)(m0 + r) * DIM + n] = acc[i][j][r] + bi;
        }
    }
}

// ---------------------------------------------------------------------------
// Kernel B: SINGLE-PASS attention with SWAPPED QK^T (mfma(K,Q)): C layout
// becomes row=key, col=q, so each lane's 16 score values belong to ONE q-row:
// per-lane scalar lsum/e0/e1 (2 shfl_xor at the end), scalar relL/relR,
// single-row qrel lookups, P packed 4 keys -> one ds_write_b64 per sub,
// per-wave u64 mask words.  Deferred normalization as in r12.
// ---------------------------------------------------------------------------
__global__ __launch_bounds__(128) void attn_mfma(
    const ushort* __restrict__ qb, const ushort* __restrict__ kb,
    const ushort* __restrict__ vtb,
    const uint8_t* __restrict__ mtok, const uint8_t* __restrict__ mstm,
    const float* __restrict__ relk, const float* __restrict__ relv,
    const float* __restrict__ smk,  const float* __restrict__ smv,
    float* __restrict__ attn_out,
    ushort* __restrict__ ctxh, ushort* __restrict__ ctxl)
{
    __shared__ ushort qrel[32][72];
    __shared__ ushort Pfull[32][648];   // unnormalized exp(score), bf16
    __shared__ ushort wbin[32][72];
    __shared__ float  linv[32];
    __shared__ float  ebuf[32];
    __shared__ uint64_t mlds[2][10];

    const int t    = threadIdx.x;
    const int lane = t & 63, w = t >> 6;
    const int swz  = ((blockIdx.x & 7) * 320) + (blockIdx.x >> 3);  // XCD-contiguous
    const int qt = swz % 20, bh = swz / 20;
    const int b = bh >> 4, h = bh & 15;
    const int qbase = qt * 32;
    const bool qstm = (qt >= 16);
    const size_t bhoff = (size_t)bh * (SS * HD);
    const int wq = w * 16, lg = lane >> 4, lc = lane & 15;
    const int RR = qstm ? 16 : 32;
    const int NV = qstm ? 33 : 65;
    const float* tabk = qstm ? smk : relk;

    // zero this wave's wbin rows (own rows only -> no barrier needed)
    for (int i = lane; i < 16 * 36; i += 64) {
        int r = i / 36, c = i - r * 36;
        *reinterpret_cast<uint32_t*>(&wbin[wq + r][c * 2]) = 0u;
    }

    // per-wave mask words: bit j of mlds[w][kt] covers key kt*64+j
    if (lane < 10) {
        uint64_t m = 0;
        const int kb0 = lane * 64;
#pragma unroll
        for (int j = 0; j < 64; ++j) {
            int kg = kb0 + j;
            uint8_t mb = (kg < STOK) ? mtok[b * STOK + kg] : mstm[b * STMN + kg - STOK];
            m |= ((uint64_t)(mb ? 1u : 0u)) << j;
        }
        mlds[w][lane] = m;
    }

    // stm blocks: zero attn cols 0..511 (scores are -inf there)
    if (qstm) {
        float4 z = make_float4(0.f, 0.f, 0.f, 0.f);
        float* dst = attn_out + ((size_t)bh * SS + qbase) * SS;
        for (int idx = t; idx < 32 * 128; idx += 128) {
            int r = idx >> 7, c4 = idx & 127;
            *reinterpret_cast<float4*>(&dst[(size_t)r * SS + c4 * 4]) = z;
        }
    }

    // Q fragments (row = qbase+wq+lc): used as B-operand in swapped QK^T
    const int qrow = qbase + wq + lc;
    v8s aq0 = *reinterpret_cast<const v8s*>(&qb[bhoff + (size_t)qrow * HD + lg * 8]);
    v8s aq1 = *reinterpret_cast<const v8s*>(&qb[bhoff + (size_t)qrow * HD + 32 + lg * 8]);

    // qrel[i][v] = q_i . rel_emb_k[v] via MFMA (wave's own 16 rows; orig order)
    {
        const int ndt = qstm ? 2 : 4;
        for (int dt = 0; dt < ndt; ++dt) {
            const float* rp = tabk + (size_t)(dt * 16 + lc) * HD;
            v8s bk0, bk1;
#pragma unroll
            for (int j = 0; j < 8; ++j) {
                bk0[j] = (short)f2b(rp[lg * 8 + j]);
                bk1[j] = (short)f2b(rp[32 + lg * 8 + j]);
            }
            v4f c4 = {0.f, 0.f, 0.f, 0.f};
            c4 = __builtin_amdgcn_mfma_f32_16x16x32_bf16(aq0, bk0, c4, 0, 0, 0);
            c4 = __builtin_amdgcn_mfma_f32_16x16x32_bf16(aq1, bk1, c4, 0, 0, 0);
#pragma unroll
            for (int r = 0; r < 4; ++r)
                qrel[wq + lg * 4 + r][dt * 16 + lc] = f2b(c4[r]);
        }
        // last column v = NV-1 (row NV-1 of table), scalar partial + shfl
        const float* rp = tabk + (size_t)(NV - 1) * HD;
        float part = 0.f;
#pragma unroll
        for (int j = 0; j < 8; ++j) {
            part += b2f((ushort)aq0[j]) * rp[lg * 8 + j];
            part += b2f((ushort)aq1[j]) * rp[32 + lg * 8 + j];
        }
        part += __shfl_xor(part, 16);
        part += __shfl_xor(part, 32);
        if (lg == 0) qrel[wq + lc][NV - 1] = f2b(part);
    }

    // per-lane scalars for this lane's single q-row
    const int gq = qbase + wq + lc;
    const float relLs = b2f(qrel[wq + lc][0]);
    const float relRs = b2f(qrel[wq + lc][2 * RR]);

    const int tile0 = qstm ? 8 : 0;
    float lsum1 = 0.f, e0 = 0.f, e1 = 0.f;
    v4f o[4];
#pragma unroll
    for (int dt = 0; dt < 4; ++dt) o[dt] = (v4f){0.f, 0.f, 0.f, 0.f};
    float* arow = attn_out + ((size_t)bh * SS + qbase) * SS;

    // ---- single fused sweep: swapped scores -> unnorm exp -> stage -> PV ----
    for (int kt = tile0; kt < 10; ++kt) {
        const ushort* kbase = kb + bhoff + (size_t)(kt * 64) * HD;
        const bool dorel = qstm || (kt < 8);
        const uint64_t mw = mlds[w][kt];
#pragma unroll
        for (int sub = 0; sub < 4; ++sub) {
            v8s bk0 = *reinterpret_cast<const v8s*>(&kbase[(sub * 16 + lc) * HD + lg * 8]);
            v8s bk1 = *reinterpret_cast<const v8s*>(&kbase[(sub * 16 + lc) * HD + 32 + lg * 8]);
            // SWAPPED: A = K-frag, B = Q-frag  ->  C[row=key][col=q]
            v4f c4 = {0.f, 0.f, 0.f, 0.f};
            c4 = __builtin_amdgcn_mfma_f32_16x16x32_bf16(bk0, aq0, c4, 0, 0, 0);
            c4 = __builtin_amdgcn_mfma_f32_16x16x32_bf16(bk1, aq1, c4, 0, 0, 0);
            const int kgb = kt * 64 + sub * 16 + lg * 4;   // lane's 4 consecutive keys
            float p4[4];
#pragma unroll
            for (int r = 0; r < 4; ++r) {
                int kg = kgb + r;
                int dlt = kg - gq;
                bool inband = dorel && (dlt > -RR) && (dlt < RR);
                float val = c4[r];
                if (dorel) {
                    float rv;
                    if (inband) rv = b2f(qrel[wq + lc][dlt + RR]);
                    else        rv = (dlt <= -RR) ? relLs : relRs;
                    val += rv;
                }
                if ((mw >> (sub * 16 + lg * 4 + r)) & 1) val = NEGINF;
                float p = __expf(val);              // UNNORMALIZED
                lsum1 += p;
                p4[r] = p;
                if (inband) wbin[wq + lc][dlt + RR] = f2b(p);
                else if (dorel) {
                    if (dlt <= -RR) e0 += p;
                    else            e1 += p;
                }
            }
            // pack 4 keys -> one b64 LDS write
            uint32_t lo = (uint32_t)f2b(p4[0]) | ((uint32_t)f2b(p4[1]) << 16);
            uint32_t hi = (uint32_t)f2b(p4[2]) | ((uint32_t)f2b(p4[3]) << 16);
            uint64_t pk64 = (uint64_t)lo | ((uint64_t)hi << 32);
            *reinterpret_cast<uint64_t*>(&Pfull[wq + lc][kgb]) = pk64;
        }
        // PV for this tile (A from own wave's Pfull rows, B = V^T frags)
        v8s ap0 = *reinterpret_cast<const v8s*>(&Pfull[wq + lc][kt * 64 + lg * 8]);
        v8s ap1 = *reinterpret_cast<const v8s*>(&Pfull[wq + lc][kt * 64 + 32 + lg * 8]);
        const ushort* vbase = vtb + bhoff + kt * 64;
#pragma unroll
        for (int dt = 0; dt < 4; ++dt) {
            v8s bv0 = *reinterpret_cast<const v8s*>(&vbase[(size_t)(dt * 16 + lc) * SS + lg * 8]);
            v8s bv1 = *reinterpret_cast<const v8s*>(&vbase[(size_t)(dt * 16 + lc) * SS + 32 + lg * 8]);
            o[dt] = __builtin_amdgcn_mfma_f32_16x16x32_bf16(ap0, bv0, o[dt], 0, 0, 0);
            o[dt] = __builtin_amdgcn_mfma_f32_16x16x32_bf16(ap1, bv1, o[dt], 0, 0, 0);
        }
    }

    // per-lane reduces: sum the 4 lg-groups of each q-column
    {
        float s = lsum1;
        s += __shfl_xor(s, 16); s += __shfl_xor(s, 32);
        float e0s = e0;
        e0s += __shfl_xor(e0s, 16); e0s += __shfl_xor(e0s, 32);
        float e1s = e1;
        e1s += __shfl_xor(e1s, 16); e1s += __shfl_xor(e1s, 32);
        if (lg == 0) {
            linv[wq + lc] = 1.f / s;
            ebuf[wq + lc] = e1s;
            wbin[wq + lc][0] = f2b(e0s);
            if (qstm) wbin[wq + lc][32] = f2b(e1s);
        }
    }

    // ---- dense normalize+write of the attn tensor (pure streaming) ----
    for (int kt = tile0; kt < 10; ++kt) {
#pragma unroll
        for (int rr = 0; rr < 4; ++rr) {
            int row = wq + rr * 4 + lg;
            float iv = linv[row];
            ushort4 pk = *reinterpret_cast<ushort4*>(&Pfull[row][kt * 64 + lc * 4]);
            float4 pv4;
            pv4.x = b2f(pk.x) * iv;
            pv4.y = b2f(pk.y) * iv;
            pv4.z = b2f(pk.z) * iv;
            pv4.w = b2f(pk.w) * iv;
            *reinterpret_cast<float4*>(&arow[(size_t)row * SS + kt * 64 + lc * 4]) = pv4;
        }
    }

    // ---- rel-v virtual tile: stage relv^T into a [64][72] view of Pfull ----
    __syncthreads();
    {
        ushort* Rv = &Pfull[0][0];
        const float* tabv = qstm ? smv : relv;
        for (int idx = t; idx < 64 * 64; idx += 128) {
            int d = idx >> 6, v = idx & 63;
            float f = (v < NV) ? tabv[(size_t)v * HD + d] : 0.f;
            Rv[d * 72 + v] = f2b(f);
        }
    }
    __syncthreads();
    {
        const ushort* Rv = &Pfull[0][0];
        v8s aw0 = *reinterpret_cast<const v8s*>(&wbin[wq + lc][lg * 8]);
        v8s aw1 = *reinterpret_cast<const v8s*>(&wbin[wq + lc][32 + lg * 8]);
#pragma unroll
        for (int dt = 0; dt < 4; ++dt) {
            v8s bv0 = *reinterpret_cast<const v8s*>(&Rv[(dt * 16 + lc) * 72 + lg * 8]);
            v8s bv1 = *reinterpret_cast<const v8s*>(&Rv[(dt * 16 + lc) * 72 + 32 + lg * 8]);
            o[dt] = __builtin_amdgcn_mfma_f32_16x16x32_bf16(aw0, bv0, o[dt], 0, 0, 0);
            o[dt] = __builtin_amdgcn_mfma_f32_16x16x32_bf16(aw1, bv1, o[dt], 0, 0, 0);
        }
        if (!qstm) {   // rank-1 fixup for bin v=64 (per C-row e1 from ebuf)
#pragma unroll
            for (int r = 0; r < 4; ++r) {
                float e1r = ebuf[wq + lg * 4 + r];
#pragma unroll
                for (int dt = 0; dt < 4; ++dt)
                    o[dt][r] += e1r * relv[(size_t)64 * HD + dt * 16 + lc];
            }
        }
    }

    // normalize o and write ctx as bf16 hi/lo [b][s][h*64+d]
    float invr[4];
#pragma unroll
    for (int r = 0; r < 4; ++r) invr[r] = linv[wq + lg * 4 + r];
#pragma unroll
    for (int dt = 0; dt < 4; ++dt)
#pragma unroll
        for (int r = 0; r < 4; ++r) {
            int gq2 = qbase + wq + lg * 4 + r;
            size_t idx = ((size_t)b * SS + gq2) * DIM + h * HD + dt * 16 + lc;
            float v = o[dt][r] * invr[r];
            ushort hi = f2b(v);
            ctxh[idx] = hi;
            ctxl[idx] = f2b(v - b2f(hi));
        }
}

// ---------------------------------------------------------------------------
extern "C" void kernel_launch(void* const* d_in, const int* in_sizes, int n_in,
                              void* d_out, int out_size, void* d_ws, size_t ws_size,
                              hipStream_t stream)
{
    const float*   stok  = (const float*)d_in[0];
    const float*   stm   = (const float*)d_in[1];
    const uint8_t* mtok  = (const uint8_t*)d_in[2];
    const uint8_t* mstm  = (const uint8_t*)d_in[3];
    const float*   qkv_w = (const float*)d_in[4];
    const float*   qkv_b = (const float*)d_in[5];
    const float*   out_w = (const float*)d_in[6];
    const float*   out_b = (const float*)d_in[7];
    const float*   relk  = (const float*)d_in[8];
    const float*   relv  = (const float*)d_in[9];
    const float*   smk   = (const float*)d_in[10];
    const float*   smv   = (const float*)d_in[11];

    float* out_final = (float*)d_out;
    float* out_attn  = out_final + (size_t)BB * SS * DIM;

    const size_t SZ = (size_t)BB * HH * SS * HD;           // 5,242,880
    ushort* qb16 = (ushort*)d_ws;
    ushort* kb16 = qb16 + SZ;
    ushort* vt16 = kb16 + SZ;
    ushort* xb16 = vt16 + SZ;                              // 5,242,880 ushorts
    ushort* wb16 = xb16 + SZ;                              // 3,145,728 ushorts
    ushort* ctxh = wb16 + (size_t)3 * DIM * DIM;
    ushort* ctxl = ctxh + SZ;
    ushort* woh  = ctxl + SZ;                              // 1,048,576 ushorts
    ushort* wol  = woh + (size_t)DIM * DIM;

    cvt_bf16<<<dim3(9216), dim3(256), 0, stream>>>(stok, stm, qkv_w, out_w,
                                                   xb16, wb16, woh, wol);
    gemm_qkv_mfma<<<dim3(1920), dim3(256), 0, stream>>>(xb16, wb16, qkv_b, qb16, kb16, vt16);
    attn_mfma<<<dim3(2560), dim3(128), 0, stream>>>(qb16, kb16, vt16, mtok, mstm,
                                                    relk, relv, smk, smv, out_attn, ctxh, ctxl);
    gemm_out_mfma<<<dim3(1280), dim3(256), 0, stream>>>(ctxh, ctxl, woh, wol, out_b, out_final);
}

// Round 16
// 297.642 us; speedup vs baseline: 1.0337x; 1.0337x over previous
//
#include <hip/hip_runtime.h>
#include <stdint.h>

// Problem constants
#define BB    8
#define HH    16
#define SS    640
#define STOK  512
#define STMN  128
#define HD    64
#define DIM   1024
#define NEGINF (-1e18f)

typedef short v8s __attribute__((ext_vector_type(8)));
typedef float v4f __attribute__((ext_vector_type(4)));

static __device__ __forceinline__ ushort f2b(float f) {
    union { float f; uint32_t u; } x; x.f = f;
    uint32_t u = (x.u + 0x7FFFu + ((x.u >> 16) & 1u)) >> 16;
    return (ushort)u;
}
static __device__ __forceinline__ float b2f(ushort h) {
    union { uint32_t u; float f; } x; x.u = ((uint32_t)h) << 16;
    return x.f;
}

// async global->LDS, 16 B per lane; dest is wave-uniform base + lane*16
static __device__ __forceinline__ void gld16(const ushort* g, ushort* l) {
    __builtin_amdgcn_global_load_lds(
        (const __attribute__((address_space(1))) unsigned int*)g,
        (__attribute__((address_space(3))) unsigned int*)l, 16, 0, 0);
}

// ---------------------------------------------------------------------------
// Kernel A0: convert x (stok||stm, [5120][1024]) and qkv_w ([3072][1024]) to
// bf16; split out_w ([1024][1024]) into bf16 hi/lo pair.  Pure streaming.
// ---------------------------------------------------------------------------
__global__ __launch_bounds__(256) void cvt_bf16(
    const float* __restrict__ stok, const float* __restrict__ stm,
    const float* __restrict__ W, const float* __restrict__ Wo,
    ushort* __restrict__ xb, ushort* __restrict__ Wb,
    ushort* __restrict__ Woh, ushort* __restrict__ Wol)
{
    const int i = blockIdx.x * 256 + threadIdx.x;
    const int XG = 5120 * 256;                      // float4-groups in x
    const int WG = 3072 * 256;                      // float4-groups in qkv_w
    if (i < XG + WG) {
        float4 v; ushort* dst;
        if (i < XG) {
            int row = i >> 8, g = i & 255;
            int b = row / SS, s = row % SS;
            const float* src = (s < STOK)
                ? stok + ((size_t)b * STOK + s) * DIM
                : stm  + ((size_t)b * STMN + (s - STOK)) * DIM;
            v = *reinterpret_cast<const float4*>(src + g * 4);
            dst = xb + (size_t)row * DIM + g * 4;
        } else {
            int j = i - XG;
            int row = j >> 8, g = j & 255;
            v = *reinterpret_cast<const float4*>(W + (size_t)row * DIM + g * 4);
            dst = Wb + (size_t)row * DIM + g * 4;
        }
        ushort4 o;
        o.x = f2b(v.x); o.y = f2b(v.y); o.z = f2b(v.z); o.w = f2b(v.w);
        *reinterpret_cast<ushort4*>(dst) = o;
    } else {
        int j = i - XG - WG;
        int row = j >> 8, g = j & 255;
        float4 v = *reinterpret_cast<const float4*>(Wo + (size_t)row * DIM + g * 4);
        ushort4 hi, lo;
        hi.x = f2b(v.x); lo.x = f2b(v.x - b2f(hi.x));
        hi.y = f2b(v.y); lo.y = f2b(v.y - b2f(hi.y));
        hi.z = f2b(v.z); lo.z = f2b(v.z - b2f(hi.z));
        hi.w = f2b(v.w); lo.w = f2b(v.w - b2f(hi.w));
        *reinterpret_cast<ushort4*>(&Woh[(size_t)row * DIM + g * 4]) = hi;
        *reinterpret_cast<ushort4*>(&Wol[(size_t)row * DIM + g * 4]) = lo;
    }
}

// ---------------------------------------------------------------------------
// Kernel A: QKV projection, m97-style LDS-staged MFMA GEMM (unchanged r13).
// ---------------------------------------------------------------------------
__global__ __launch_bounds__(256) void gemm_qkv_mfma(
    const ushort* __restrict__ xb, const ushort* __restrict__ Wb,
    const float* __restrict__ bias,
    ushort* __restrict__ qb, ushort* __restrict__ kb, ushort* __restrict__ vtb)
{
    __shared__ __align__(16) ushort As[64 * 32];     // 4 KB
    __shared__ __align__(16) ushort Bs[128 * 32];    // 8 KB
    const int t = threadIdx.x, lane = t & 63, w = t >> 6;
    const int swz = ((blockIdx.x & 7) * 240) + (blockIdx.x >> 3);
    const int nt = swz / 80, mt = swz % 80;
    const int mb = mt * 64, nb = nt * 128;
    const int wm = (w >> 1) * 32, wn = (w & 1) * 64;
    const int lg = lane >> 4, lc = lane & 15;

    const int ra = t >> 2, pa = t & 3;
    const ushort* gA = xb + (size_t)(mb + ra) * DIM + (pa ^ ((ra >> 1) & 3)) * 8;
    ushort* lA = As + (w * 64) * 8;
    const ushort* gB[2]; ushort* lB[2];
#pragma unroll
    for (int i = 0; i < 2; ++i) {
        int c = t + i * 256, rb = c >> 2, pb = c & 3;
        gB[i] = Wb + (size_t)(nb + rb) * DIM + (pb ^ ((rb >> 1) & 3)) * 8;
        lB[i] = Bs + (i * 256 + w * 64) * 8;
    }

    v4f acc[2][4];
#pragma unroll
    for (int i = 0; i < 2; ++i)
#pragma unroll
        for (int j = 0; j < 4; ++j) acc[i][j] = (v4f){0.f, 0.f, 0.f, 0.f};

    for (int kt = 0; kt < 32; ++kt) {
        const int ko = kt * 32;
        __syncthreads();
        gld16(gA + ko, lA);
        gld16(gB[0] + ko, lB[0]);
        gld16(gB[1] + ko, lB[1]);
        __syncthreads();
        v8s af[2], bf[4];
#pragma unroll
        for (int i = 0; i < 2; ++i) {
            int ar = wm + i * 16 + lc;
            af[i] = *reinterpret_cast<const v8s*>(&As[ar * 32 + (lg ^ ((ar >> 1) & 3)) * 8]);
        }
#pragma unroll
        for (int j = 0; j < 4; ++j) {
            int br = wn + j * 16 + lc;
            bf[j] = *reinterpret_cast<const v8s*>(&Bs[br * 32 + (lg ^ ((br >> 1) & 3)) * 8]);
        }
#pragma unroll
        for (int i = 0; i < 2; ++i)
#pragma unroll
            for (int j = 0; j < 4; ++j)
                acc[i][j] = __builtin_amdgcn_mfma_f32_16x16x32_bf16(af[i], bf[j], acc[i][j], 0, 0, 0);
    }

    const int nregion = nb >> 10;                  // 0=q 1=k 2=v
    if (nregion < 2) {
        ushort* dst = nregion ? kb : qb;
        const float scale = nregion ? 1.0f : 0.125f;
#pragma unroll
        for (int j = 0; j < 4; ++j) {
            int n = nb + wn + j * 16 + lc;
            int nn = n & 1023, h = nn >> 6, d = nn & 63;
            float bi = bias[n];
#pragma unroll
            for (int i = 0; i < 2; ++i) {
                int m0 = mb + wm + i * 16 + lg * 4;
                int b = m0 / SS, s0 = m0 % SS;
                size_t base = (((size_t)b * HH + h) * SS + s0) * HD + d;
#pragma unroll
                for (int r = 0; r < 4; ++r)
                    dst[base + (size_t)r * HD] = f2b((acc[i][j][r] + bi) * scale);
            }
        }
    } else {
#pragma unroll
        for (int j = 0; j < 4; ++j) {
            int n = nb + wn + j * 16 + lc;
            int nn = n & 1023, h = nn >> 6, d = nn & 63;
            float bi = bias[n];
#pragma unroll
            for (int i = 0; i < 2; ++i) {
                int m0 = mb + wm + i * 16 + lg * 4;   // 4 consecutive s, same b
                int b = m0 / SS, s0 = m0 % SS;
                ushort4 pk;
                pk.x = f2b(acc[i][j][0] + bi);
                pk.y = f2b(acc[i][j][1] + bi);
                pk.z = f2b(acc[i][j][2] + bi);
                pk.w = f2b(acc[i][j][3] + bi);
                *reinterpret_cast<ushort4*>(
                    &vtb[(((size_t)b * HH + h) * HD + d) * SS + s0]) = pk;
            }
        }
    }
}

// ---------------------------------------------------------------------------
// Kernel C: out projection, LDS-staged double-bf16 MFMA GEMM (unchanged r13).
// ---------------------------------------------------------------------------
__global__ __launch_bounds__(256) void gemm_out_mfma(
    const ushort* __restrict__ Xh, const ushort* __restrict__ Xl,
    const ushort* __restrict__ Wh, const ushort* __restrict__ Wl,
    const float* __restrict__ bias, float* __restrict__ out)
{
    __shared__ __align__(16) ushort Ah[64 * 32];
    __shared__ __align__(16) ushort Al[64 * 32];
    __shared__ __align__(16) ushort Bh[64 * 32];
    __shared__ __align__(16) ushort Bl[64 * 32];
    const int t = threadIdx.x, lane = t & 63, w = t >> 6;
    const int swz = ((blockIdx.x & 7) * 160) + (blockIdx.x >> 3);
    const int nt = swz / 80, mt = swz % 80;
    const int mb = mt * 64, nb = nt * 64;
    const int wm = (w >> 1) * 32, wn = (w & 1) * 32;
    const int lg = lane >> 4, lc = lane & 15;

    const int rr = t >> 2, pp = t & 3;
    const size_t goff = (size_t)rr * DIM + (pp ^ ((rr >> 1) & 3)) * 8;
    const ushort* gAh = Xh + (size_t)mb * DIM + goff;
    const ushort* gAl = Xl + (size_t)mb * DIM + goff;
    const ushort* gBh = Wh + (size_t)nb * DIM + goff;
    const ushort* gBl = Wl + (size_t)nb * DIM + goff;
    const int wchunk = (w * 64) * 8;

    v4f acc[2][2];
#pragma unroll
    for (int i = 0; i < 2; ++i)
#pragma unroll
        for (int j = 0; j < 2; ++j) acc[i][j] = (v4f){0.f, 0.f, 0.f, 0.f};

    for (int kt = 0; kt < 32; ++kt) {
        const int ko = kt * 32;
        __syncthreads();
        gld16(gAh + ko, Ah + wchunk);
        gld16(gAl + ko, Al + wchunk);
        gld16(gBh + ko, Bh + wchunk);
        gld16(gBl + ko, Bl + wchunk);
        __syncthreads();
        v8s ahf[2], alf[2], bhf[2], blf[2];
#pragma unroll
        for (int i = 0; i < 2; ++i) {
            int ar = wm + i * 16 + lc;
            int ao = ar * 32 + (lg ^ ((ar >> 1) & 3)) * 8;
            ahf[i] = *reinterpret_cast<const v8s*>(&Ah[ao]);
            alf[i] = *reinterpret_cast<const v8s*>(&Al[ao]);
            int br = wn + i * 16 + lc;
            int bo = br * 32 + (lg ^ ((br >> 1) & 3)) * 8;
            bhf[i] = *reinterpret_cast<const v8s*>(&Bh[bo]);
            blf[i] = *reinterpret_cast<const v8s*>(&Bl[bo]);
        }
#pragma unroll
        for (int i = 0; i < 2; ++i)
#pragma unroll
            for (int j = 0; j < 2; ++j)
                acc[i][j] = __builtin_amdgcn_mfma_f32_16x16x32_bf16(ahf[i], bhf[j], acc[i][j], 0, 0, 0);
#pragma unroll
        for (int i = 0; i < 2; ++i)
#pragma unroll
            for (int j = 0; j < 2; ++j)
                acc[i][j] = __builtin_amdgcn_mfma_f32_16x16x32_bf16(alf[i], bhf[j], acc[i][j], 0, 0, 0);
#pragma unroll
        for (int i = 0; i < 2; ++i)
#pragma unroll
            for (int j = 0; j < 2; ++j)
                acc[i][j] = __builtin_amdgcn_mfma_f32_16x16x32_bf16(ahf[i], blf[j], acc[i][j], 0, 0, 0);
    }

#pragma unroll
    for (int j = 0; j < 2; ++j) {
        int n = nb + wn + j * 16 + lc;
        float bi = bias[n];
#pragma unroll
        for (int i = 0; i < 2; ++i) {
            int m0 = mb + wm + i * 16 + lg * 4;
#pragma unroll
            for (int r = 0; r < 4; ++r)
                out[(size_t)(m0 + r) * DIM + n] = acc[i][j][r] + bi;
        }
    }
}

// ---------------------------------------------------------------------------
// Kernel B: SINGLE-PASS attention, swapped QK^T, deferred normalization.
// r16: row-contiguous attn write pass (each 16-lane group streams one full
// 2560 B row as 10 sequential 256 B bursts; qstm zero-fill merged) using
// non-temporal stores via clang ext-vector v4f (write-once data, no L2 alloc).
// ---------------------------------------------------------------------------
__global__ __launch_bounds__(128) void attn_mfma(
    const ushort* __restrict__ qb, const ushort* __restrict__ kb,
    const ushort* __restrict__ vtb,
    const uint8_t* __restrict__ mtok, const uint8_t* __restrict__ mstm,
    const float* __restrict__ relk, const float* __restrict__ relv,
    const float* __restrict__ smk,  const float* __restrict__ smv,
    float* __restrict__ attn_out,
    ushort* __restrict__ ctxh, ushort* __restrict__ ctxl)
{
    __shared__ ushort qrel[32][72];
    __shared__ ushort Pfull[32][648];   // unnormalized exp(score), bf16
    __shared__ ushort wbin[32][72];
    __shared__ float  linv[32];
    __shared__ float  ebuf[32];
    __shared__ uint64_t mlds[2][10];

    const int t    = threadIdx.x;
    const int lane = t & 63, w = t >> 6;
    const int swz  = ((blockIdx.x & 7) * 320) + (blockIdx.x >> 3);  // XCD-contiguous
    const int qt = swz % 20, bh = swz / 20;
    const int b = bh >> 4, h = bh & 15;
    const int qbase = qt * 32;
    const bool qstm = (qt >= 16);
    const size_t bhoff = (size_t)bh * (SS * HD);
    const int wq = w * 16, lg = lane >> 4, lc = lane & 15;
    const int RR = qstm ? 16 : 32;
    const int NV = qstm ? 33 : 65;
    const float* tabk = qstm ? smk : relk;

    // zero this wave's wbin rows (own rows only -> no barrier needed)
    for (int i = lane; i < 16 * 36; i += 64) {
        int r = i / 36, c = i - r * 36;
        *reinterpret_cast<uint32_t*>(&wbin[wq + r][c * 2]) = 0u;
    }

    // per-wave mask words: bit j of mlds[w][kt] covers key kt*64+j
    if (lane < 10) {
        uint64_t m = 0;
        const int kb0 = lane * 64;
#pragma unroll
        for (int j = 0; j < 64; ++j) {
            int kg = kb0 + j;
            uint8_t mb = (kg < STOK) ? mtok[b * STOK + kg] : mstm[b * STMN + kg - STOK];
            m |= ((uint64_t)(mb ? 1u : 0u)) << j;
        }
        mlds[w][lane] = m;
    }

    // Q fragments (row = qbase+wq+lc): used as B-operand in swapped QK^T
    const int qrow = qbase + wq + lc;
    v8s aq0 = *reinterpret_cast<const v8s*>(&qb[bhoff + (size_t)qrow * HD + lg * 8]);
    v8s aq1 = *reinterpret_cast<const v8s*>(&qb[bhoff + (size_t)qrow * HD + 32 + lg * 8]);

    // qrel[i][v] = q_i . rel_emb_k[v] via MFMA (wave's own 16 rows; orig order)
    {
        const int ndt = qstm ? 2 : 4;
        for (int dt = 0; dt < ndt; ++dt) {
            const float* rp = tabk + (size_t)(dt * 16 + lc) * HD;
            v8s bk0, bk1;
#pragma unroll
            for (int j = 0; j < 8; ++j) {
                bk0[j] = (short)f2b(rp[lg * 8 + j]);
                bk1[j] = (short)f2b(rp[32 + lg * 8 + j]);
            }
            v4f c4 = {0.f, 0.f, 0.f, 0.f};
            c4 = __builtin_amdgcn_mfma_f32_16x16x32_bf16(aq0, bk0, c4, 0, 0, 0);
            c4 = __builtin_amdgcn_mfma_f32_16x16x32_bf16(aq1, bk1, c4, 0, 0, 0);
#pragma unroll
            for (int r = 0; r < 4; ++r)
                qrel[wq + lg * 4 + r][dt * 16 + lc] = f2b(c4[r]);
        }
        // last column v = NV-1 (row NV-1 of table), scalar partial + shfl
        const float* rp = tabk + (size_t)(NV - 1) * HD;
        float part = 0.f;
#pragma unroll
        for (int j = 0; j < 8; ++j) {
            part += b2f((ushort)aq0[j]) * rp[lg * 8 + j];
            part += b2f((ushort)aq1[j]) * rp[32 + lg * 8 + j];
        }
        part += __shfl_xor(part, 16);
        part += __shfl_xor(part, 32);
        if (lg == 0) qrel[wq + lc][NV - 1] = f2b(part);
    }

    // per-lane scalars for this lane's single q-row
    const int gq = qbase + wq + lc;
    const float relLs = b2f(qrel[wq + lc][0]);
    const float relRs = b2f(qrel[wq + lc][2 * RR]);

    const int tile0 = qstm ? 8 : 0;
    float lsum1 = 0.f, e0 = 0.f, e1 = 0.f;
    v4f o[4];
#pragma unroll
    for (int dt = 0; dt < 4; ++dt) o[dt] = (v4f){0.f, 0.f, 0.f, 0.f};
    float* arow = attn_out + ((size_t)bh * SS + qbase) * SS;

    // ---- single fused sweep: swapped scores -> unnorm exp -> stage -> PV ----
    for (int kt = tile0; kt < 10; ++kt) {
        const ushort* kbase = kb + bhoff + (size_t)(kt * 64) * HD;
        const bool dorel = qstm || (kt < 8);
        const uint64_t mw = mlds[w][kt];
#pragma unroll
        for (int sub = 0; sub < 4; ++sub) {
            v8s bk0 = *reinterpret_cast<const v8s*>(&kbase[(sub * 16 + lc) * HD + lg * 8]);
            v8s bk1 = *reinterpret_cast<const v8s*>(&kbase[(sub * 16 + lc) * HD + 32 + lg * 8]);
            // SWAPPED: A = K-frag, B = Q-frag  ->  C[row=key][col=q]
            v4f c4 = {0.f, 0.f, 0.f, 0.f};
            c4 = __builtin_amdgcn_mfma_f32_16x16x32_bf16(bk0, aq0, c4, 0, 0, 0);
            c4 = __builtin_amdgcn_mfma_f32_16x16x32_bf16(bk1, aq1, c4, 0, 0, 0);
            const int kgb = kt * 64 + sub * 16 + lg * 4;   // lane's 4 consecutive keys
            float p4[4];
#pragma unroll
            for (int r = 0; r < 4; ++r) {
                int kg = kgb + r;
                int dlt = kg - gq;
                bool inband = dorel && (dlt > -RR) && (dlt < RR);
                float val = c4[r];
                if (dorel) {
                    float rv;
                    if (inband) rv = b2f(qrel[wq + lc][dlt + RR]);
                    else        rv = (dlt <= -RR) ? relLs : relRs;
                    val += rv;
                }
                if ((mw >> (sub * 16 + lg * 4 + r)) & 1) val = NEGINF;
                float p = __expf(val);              // UNNORMALIZED
                lsum1 += p;
                p4[r] = p;
                if (inband) wbin[wq + lc][dlt + RR] = f2b(p);
                else if (dorel) {
                    if (dlt <= -RR) e0 += p;
                    else            e1 += p;
                }
            }
            // pack 4 keys -> one b64 LDS write
            uint32_t lo = (uint32_t)f2b(p4[0]) | ((uint32_t)f2b(p4[1]) << 16);
            uint32_t hi = (uint32_t)f2b(p4[2]) | ((uint32_t)f2b(p4[3]) << 16);
            uint64_t pk64 = (uint64_t)lo | ((uint64_t)hi << 32);
            *reinterpret_cast<uint64_t*>(&Pfull[wq + lc][kgb]) = pk64;
        }
        // PV for this tile (A from own wave's Pfull rows, B = V^T frags)
        v8s ap0 = *reinterpret_cast<const v8s*>(&Pfull[wq + lc][kt * 64 + lg * 8]);
        v8s ap1 = *reinterpret_cast<const v8s*>(&Pfull[wq + lc][kt * 64 + 32 + lg * 8]);
        const ushort* vbase = vtb + bhoff + kt * 64;
#pragma unroll
        for (int dt = 0; dt < 4; ++dt) {
            v8s bv0 = *reinterpret_cast<const v8s*>(&vbase[(size_t)(dt * 16 + lc) * SS + lg * 8]);
            v8s bv1 = *reinterpret_cast<const v8s*>(&vbase[(size_t)(dt * 16 + lc) * SS + 32 + lg * 8]);
            o[dt] = __builtin_amdgcn_mfma_f32_16x16x32_bf16(ap0, bv0, o[dt], 0, 0, 0);
            o[dt] = __builtin_amdgcn_mfma_f32_16x16x32_bf16(ap1, bv1, o[dt], 0, 0, 0);
        }
    }

    // per-lane reduces: sum the 4 lg-groups of each q-column
    {
        float s = lsum1;
        s += __shfl_xor(s, 16); s += __shfl_xor(s, 32);
        float e0s = e0;
        e0s += __shfl_xor(e0s, 16); e0s += __shfl_xor(e0s, 32);
        float e1s = e1;
        e1s += __shfl_xor(e1s, 16); e1s += __shfl_xor(e1s, 32);
        if (lg == 0) {
            linv[wq + lc] = 1.f / s;
            ebuf[wq + lc] = e1s;
            wbin[wq + lc][0] = f2b(e0s);
            if (qstm) wbin[wq + lc][32] = f2b(e1s);
        }
    }

    // ---- row-contiguous normalize+write of the attn tensor (nt stores) ----
    // each 16-lane group streams one full row: 10 sequential 256 B bursts.
#pragma unroll
    for (int rr = 0; rr < 4; ++rr) {
        int row = wq + rr * 4 + lg;
        float iv = linv[row];
        float* rowp = arow + (size_t)row * SS;
        if (qstm) {
            v4f z = (v4f){0.f, 0.f, 0.f, 0.f};
#pragma unroll
            for (int kt = 0; kt < 8; ++kt)
                __builtin_nontemporal_store(z,
                    reinterpret_cast<v4f*>(&rowp[kt * 64 + lc * 4]));
#pragma unroll
            for (int kt = 8; kt < 10; ++kt) {
                ushort4 pk = *reinterpret_cast<ushort4*>(&Pfull[row][kt * 64 + lc * 4]);
                v4f pv4;
                pv4[0] = b2f(pk.x) * iv;
                pv4[1] = b2f(pk.y) * iv;
                pv4[2] = b2f(pk.z) * iv;
                pv4[3] = b2f(pk.w) * iv;
                __builtin_nontemporal_store(pv4,
                    reinterpret_cast<v4f*>(&rowp[kt * 64 + lc * 4]));
            }
        } else {
#pragma unroll
            for (int kt = 0; kt < 10; ++kt) {
                ushort4 pk = *reinterpret_cast<ushort4*>(&Pfull[row][kt * 64 + lc * 4]);
                v4f pv4;
                pv4[0] = b2f(pk.x) * iv;
                pv4[1] = b2f(pk.y) * iv;
                pv4[2] = b2f(pk.z) * iv;
                pv4[3] = b2f(pk.w) * iv;
                __builtin_nontemporal_store(pv4,
                    reinterpret_cast<v4f*>(&rowp[kt * 64 + lc * 4]));
            }
        }
    }

    // ---- rel-v virtual tile: stage relv^T into a [64][72] view of Pfull ----
    __syncthreads();
    {
        ushort* Rv = &Pfull[0][0];
        const float* tabv = qstm ? smv : relv;
        for (int idx = t; idx < 64 * 64; idx += 128) {
            int d = idx >> 6, v = idx & 63;
            float f = (v < NV) ? tabv[(size_t)v * HD + d] : 0.f;
            Rv[d * 72 + v] = f2b(f);
        }
    }
    __syncthreads();
    {
        const ushort* Rv = &Pfull[0][0];
        v8s aw0 = *reinterpret_cast<const v8s*>(&wbin[wq + lc][lg * 8]);
        v8s aw1 = *reinterpret_cast<const v8s*>(&wbin[wq + lc][32 + lg * 8]);
#pragma unroll
        for (int dt = 0; dt < 4; ++dt) {
            v8s bv0 = *reinterpret_cast<const v8s*>(&Rv[(dt * 16 + lc) * 72 + lg * 8]);
            v8s bv1 = *reinterpret_cast<const v8s*>(&Rv[(dt * 16 + lc) * 72 + 32 + lg * 8]);
            o[dt] = __builtin_amdgcn_mfma_f32_16x16x32_bf16(aw0, bv0, o[dt], 0, 0, 0);
            o[dt] = __builtin_amdgcn_mfma_f32_16x16x32_bf16(aw1, bv1, o[dt], 0, 0, 0);
        }
        if (!qstm) {   // rank-1 fixup for bin v=64 (per C-row e1 from ebuf)
#pragma unroll
            for (int r = 0; r < 4; ++r) {
                float e1r = ebuf[wq + lg * 4 + r];
#pragma unroll
                for (int dt = 0; dt < 4; ++dt)
                    o[dt][r] += e1r * relv[(size_t)64 * HD + dt * 16 + lc];
            }
        }
    }

    // normalize o and write ctx as bf16 hi/lo [b][s][h*64+d]
    float invr[4];
#pragma unroll
    for (int r = 0; r < 4; ++r) invr[r] = linv[wq + lg * 4 + r];
#pragma unroll
    for (int dt = 0; dt < 4; ++dt)
#pragma unroll
        for (int r = 0; r < 4; ++r) {
            int gq2 = qbase + wq + lg * 4 + r;
            size_t idx = ((size_t)b * SS + gq2) * DIM + h * HD + dt * 16 + lc;
            float v = o[dt][r] * invr[r];
            ushort hi = f2b(v);
            ctxh[idx] = hi;
            ctxl[idx] = f2b(v - b2f(hi));
        }
}

// ---------------------------------------------------------------------------
extern "C" void kernel_launch(void* const* d_in, const int* in_sizes, int n_in,
                              void* d_out, int out_size, void* d_ws, size_t ws_size,
                              hipStream_t stream)
{
    const float*   stok  = (const float*)d_in[0];
    const float*   stm   = (const float*)d_in[1];
    const uint8_t* mtok  = (const uint8_t*)d_in[2];
    const uint8_t* mstm  = (const uint8_t*)d_in[3];
    const float*   qkv_w = (const float*)d_in[4];
    const float*   qkv_b = (const float*)d_in[5];
    const float*   out_w = (const float*)d_in[6];
    const float*   out_b = (const float*)d_in[7];
    const float*   relk  = (const float*)d_in[8];
    const float*   relv  = (const float*)d_in[9];
    const float*   smk   = (const float*)d_in[10];
    const float*   smv   = (const float*)d_in[11];

    float* out_final = (float*)d_out;
    float* out_attn  = out_final + (size_t)BB * SS * DIM;

    const size_t SZ = (size_t)BB * HH * SS * HD;           // 5,242,880
    ushort* qb16 = (ushort*)d_ws;
    ushort* kb16 = qb16 + SZ;
    ushort* vt16 = kb16 + SZ;
    ushort* xb16 = vt16 + SZ;                              // 5,242,880 ushorts
    ushort* wb16 = xb16 + SZ;                              // 3,145,728 ushorts
    ushort* ctxh = wb16 + (size_t)3 * DIM * DIM;
    ushort* ctxl = ctxh + SZ;
    ushort* woh  = ctxl + SZ;                              // 1,048,576 ushorts
    ushort* wol  = woh + (size_t)DIM * DIM;

    cvt_bf16<<<dim3(9216), dim3(256), 0, stream>>>(stok, stm, qkv_w, out_w,
                                                   xb16, wb16, woh, wol);
    gemm_qkv_mfma<<<dim3(1920), dim3(256), 0, stream>>>(xb16, wb16, qkv_b, qb16, kb16, vt16);
    attn_mfma<<<dim3(2560), dim3(128), 0, stream>>>(qb16, kb16, vt16, mtok, mstm,
                                                    relk, relv, smk, smv, out_attn, ctxh, ctxl);
    gemm_out_mfma<<<dim3(1280), dim3(256), 0, stream>>>(ctxh, ctxl, woh, wol, out_b, out_final);
}

// Round 17
// 263.684 us; speedup vs baseline: 1.1668x; 1.1288x over previous
//
#include <hip/hip_runtime.h>
#include <stdint.h>

// Problem constants
#define BB    8
#define HH    16
#define SS    640
#define STOK  512
#define STMN  128
#define HD    64
#define DIM   1024
#define NEGINF (-1e18f)

typedef short v8s __attribute__((ext_vector_type(8)));
typedef float v4f __attribute__((ext_vector_type(4)));

static __device__ __forceinline__ ushort f2b(float f) {
    union { float f; uint32_t u; } x; x.f = f;
    uint32_t u = (x.u + 0x7FFFu + ((x.u >> 16) & 1u)) >> 16;
    return (ushort)u;
}
static __device__ __forceinline__ float b2f(ushort h) {
    union { uint32_t u; float f; } x; x.u = ((uint32_t)h) << 16;
    return x.f;
}

// async global->LDS, 16 B per lane; dest is wave-uniform base + lane*16
static __device__ __forceinline__ void gld16(const ushort* g, ushort* l) {
    __builtin_amdgcn_global_load_lds(
        (const __attribute__((address_space(1))) unsigned int*)g,
        (__attribute__((address_space(3))) unsigned int*)l, 16, 0, 0);
}

// ---------------------------------------------------------------------------
// Kernel A0: convert x and qkv_w to bf16; split out_w into bf16 hi/lo.
// ---------------------------------------------------------------------------
__global__ __launch_bounds__(256) void cvt_bf16(
    const float* __restrict__ stok, const float* __restrict__ stm,
    const float* __restrict__ W, const float* __restrict__ Wo,
    ushort* __restrict__ xb, ushort* __restrict__ Wb,
    ushort* __restrict__ Woh, ushort* __restrict__ Wol)
{
    const int i = blockIdx.x * 256 + threadIdx.x;
    const int XG = 5120 * 256;                      // float4-groups in x
    const int WG = 3072 * 256;                      // float4-groups in qkv_w
    if (i < XG + WG) {
        float4 v; ushort* dst;
        if (i < XG) {
            int row = i >> 8, g = i & 255;
            int b = row / SS, s = row % SS;
            const float* src = (s < STOK)
                ? stok + ((size_t)b * STOK + s) * DIM
                : stm  + ((size_t)b * STMN + (s - STOK)) * DIM;
            v = *reinterpret_cast<const float4*>(src + g * 4);
            dst = xb + (size_t)row * DIM + g * 4;
        } else {
            int j = i - XG;
            int row = j >> 8, g = j & 255;
            v = *reinterpret_cast<const float4*>(W + (size_t)row * DIM + g * 4);
            dst = Wb + (size_t)row * DIM + g * 4;
        }
        ushort4 o;
        o.x = f2b(v.x); o.y = f2b(v.y); o.z = f2b(v.z); o.w = f2b(v.w);
        *reinterpret_cast<ushort4*>(dst) = o;
    } else {
        int j = i - XG - WG;
        int row = j >> 8, g = j & 255;
        float4 v = *reinterpret_cast<const float4*>(Wo + (size_t)row * DIM + g * 4);
        ushort4 hi, lo;
        hi.x = f2b(v.x); lo.x = f2b(v.x - b2f(hi.x));
        hi.y = f2b(v.y); lo.y = f2b(v.y - b2f(hi.y));
        hi.z = f2b(v.z); lo.z = f2b(v.z - b2f(hi.z));
        hi.w = f2b(v.w); lo.w = f2b(v.w - b2f(hi.w));
        *reinterpret_cast<ushort4*>(&Woh[(size_t)row * DIM + g * 4]) = hi;
        *reinterpret_cast<ushort4*>(&Wol[(size_t)row * DIM + g * 4]) = lo;
    }
}

// ---------------------------------------------------------------------------
// Kernel A: QKV projection, LDS-staged MFMA GEMM (unchanged r13).
// ---------------------------------------------------------------------------
__global__ __launch_bounds__(256) void gemm_qkv_mfma(
    const ushort* __restrict__ xb, const ushort* __restrict__ Wb,
    const float* __restrict__ bias,
    ushort* __restrict__ qb, ushort* __restrict__ kb, ushort* __restrict__ vtb)
{
    __shared__ __align__(16) ushort As[64 * 32];     // 4 KB
    __shared__ __align__(16) ushort Bs[128 * 32];    // 8 KB
    const int t = threadIdx.x, lane = t & 63, w = t >> 6;
    const int swz = ((blockIdx.x & 7) * 240) + (blockIdx.x >> 3);
    const int nt = swz / 80, mt = swz % 80;
    const int mb = mt * 64, nb = nt * 128;
    const int wm = (w >> 1) * 32, wn = (w & 1) * 64;
    const int lg = lane >> 4, lc = lane & 15;

    const int ra = t >> 2, pa = t & 3;
    const ushort* gA = xb + (size_t)(mb + ra) * DIM + (pa ^ ((ra >> 1) & 3)) * 8;
    ushort* lA = As + (w * 64) * 8;
    const ushort* gB[2]; ushort* lB[2];
#pragma unroll
    for (int i = 0; i < 2; ++i) {
        int c = t + i * 256, rb = c >> 2, pb = c & 3;
        gB[i] = Wb + (size_t)(nb + rb) * DIM + (pb ^ ((rb >> 1) & 3)) * 8;
        lB[i] = Bs + (i * 256 + w * 64) * 8;
    }

    v4f acc[2][4];
#pragma unroll
    for (int i = 0; i < 2; ++i)
#pragma unroll
        for (int j = 0; j < 4; ++j) acc[i][j] = (v4f){0.f, 0.f, 0.f, 0.f};

    for (int kt = 0; kt < 32; ++kt) {
        const int ko = kt * 32;
        __syncthreads();
        gld16(gA + ko, lA);
        gld16(gB[0] + ko, lB[0]);
        gld16(gB[1] + ko, lB[1]);
        __syncthreads();
        v8s af[2], bf[4];
#pragma unroll
        for (int i = 0; i < 2; ++i) {
            int ar = wm + i * 16 + lc;
            af[i] = *reinterpret_cast<const v8s*>(&As[ar * 32 + (lg ^ ((ar >> 1) & 3)) * 8]);
        }
#pragma unroll
        for (int j = 0; j < 4; ++j) {
            int br = wn + j * 16 + lc;
            bf[j] = *reinterpret_cast<const v8s*>(&Bs[br * 32 + (lg ^ ((br >> 1) & 3)) * 8]);
        }
#pragma unroll
        for (int i = 0; i < 2; ++i)
#pragma unroll
            for (int j = 0; j < 4; ++j)
                acc[i][j] = __builtin_amdgcn_mfma_f32_16x16x32_bf16(af[i], bf[j], acc[i][j], 0, 0, 0);
    }

    const int nregion = nb >> 10;                  // 0=q 1=k 2=v
    if (nregion < 2) {
        ushort* dst = nregion ? kb : qb;
        const float scale = nregion ? 1.0f : 0.125f;
#pragma unroll
        for (int j = 0; j < 4; ++j) {
            int n = nb + wn + j * 16 + lc;
            int nn = n & 1023, h = nn >> 6, d = nn & 63;
            float bi = bias[n];
#pragma unroll
            for (int i = 0; i < 2; ++i) {
                int m0 = mb + wm + i * 16 + lg * 4;
                int b = m0 / SS, s0 = m0 % SS;
                size_t base = (((size_t)b * HH + h) * SS + s0) * HD + d;
#pragma unroll
                for (int r = 0; r < 4; ++r)
                    dst[base + (size_t)r * HD] = f2b((acc[i][j][r] + bi) * scale);
            }
        }
    } else {
#pragma unroll
        for (int j = 0; j < 4; ++j) {
            int n = nb + wn + j * 16 + lc;
            int nn = n & 1023, h = nn >> 6, d = nn & 63;
            float bi = bias[n];
#pragma unroll
            for (int i = 0; i < 2; ++i) {
                int m0 = mb + wm + i * 16 + lg * 4;   // 4 consecutive s, same b
                int b = m0 / SS, s0 = m0 % SS;
                ushort4 pk;
                pk.x = f2b(acc[i][j][0] + bi);
                pk.y = f2b(acc[i][j][1] + bi);
                pk.z = f2b(acc[i][j][2] + bi);
                pk.w = f2b(acc[i][j][3] + bi);
                *reinterpret_cast<ushort4*>(
                    &vtb[(((size_t)b * HH + h) * HD + d) * SS + s0]) = pk;
            }
        }
    }
}

// ---------------------------------------------------------------------------
// Kernel C: out projection, LDS-staged double-bf16 MFMA GEMM (unchanged r13).
// ---------------------------------------------------------------------------
__global__ __launch_bounds__(256) void gemm_out_mfma(
    const ushort* __restrict__ Xh, const ushort* __restrict__ Xl,
    const ushort* __restrict__ Wh, const ushort* __restrict__ Wl,
    const float* __restrict__ bias, float* __restrict__ out)
{
    __shared__ __align__(16) ushort Ah[64 * 32];
    __shared__ __align__(16) ushort Al[64 * 32];
    __shared__ __align__(16) ushort Bh[64 * 32];
    __shared__ __align__(16) ushort Bl[64 * 32];
    const int t = threadIdx.x, lane = t & 63, w = t >> 6;
    const int swz = ((blockIdx.x & 7) * 160) + (blockIdx.x >> 3);
    const int nt = swz / 80, mt = swz % 80;
    const int mb = mt * 64, nb = nt * 64;
    const int wm = (w >> 1) * 32, wn = (w & 1) * 32;
    const int lg = lane >> 4, lc = lane & 15;

    const int rr = t >> 2, pp = t & 3;
    const size_t goff = (size_t)rr * DIM + (pp ^ ((rr >> 1) & 3)) * 8;
    const ushort* gAh = Xh + (size_t)mb * DIM + goff;
    const ushort* gAl = Xl + (size_t)mb * DIM + goff;
    const ushort* gBh = Wh + (size_t)nb * DIM + goff;
    const ushort* gBl = Wl + (size_t)nb * DIM + goff;
    const int wchunk = (w * 64) * 8;

    v4f acc[2][2];
#pragma unroll
    for (int i = 0; i < 2; ++i)
#pragma unroll
        for (int j = 0; j < 2; ++j) acc[i][j] = (v4f){0.f, 0.f, 0.f, 0.f};

    for (int kt = 0; kt < 32; ++kt) {
        const int ko = kt * 32;
        __syncthreads();
        gld16(gAh + ko, Ah + wchunk);
        gld16(gAl + ko, Al + wchunk);
        gld16(gBh + ko, Bh + wchunk);
        gld16(gBl + ko, Bl + wchunk);
        __syncthreads();
        v8s ahf[2], alf[2], bhf[2], blf[2];
#pragma unroll
        for (int i = 0; i < 2; ++i) {
            int ar = wm + i * 16 + lc;
            int ao = ar * 32 + (lg ^ ((ar >> 1) & 3)) * 8;
            ahf[i] = *reinterpret_cast<const v8s*>(&Ah[ao]);
            alf[i] = *reinterpret_cast<const v8s*>(&Al[ao]);
            int br = wn + i * 16 + lc;
            int bo = br * 32 + (lg ^ ((br >> 1) & 3)) * 8;
            bhf[i] = *reinterpret_cast<const v8s*>(&Bh[bo]);
            blf[i] = *reinterpret_cast<const v8s*>(&Bl[bo]);
        }
#pragma unroll
        for (int i = 0; i < 2; ++i)
#pragma unroll
            for (int j = 0; j < 2; ++j)
                acc[i][j] = __builtin_amdgcn_mfma_f32_16x16x32_bf16(ahf[i], bhf[j], acc[i][j], 0, 0, 0);
#pragma unroll
        for (int i = 0; i < 2; ++i)
#pragma unroll
            for (int j = 0; j < 2; ++j)
                acc[i][j] = __builtin_amdgcn_mfma_f32_16x16x32_bf16(alf[i], bhf[j], acc[i][j], 0, 0, 0);
#pragma unroll
        for (int i = 0; i < 2; ++i)
#pragma unroll
            for (int j = 0; j < 2; ++j)
                acc[i][j] = __builtin_amdgcn_mfma_f32_16x16x32_bf16(ahf[i], blf[j], acc[i][j], 0, 0, 0);
    }

#pragma unroll
    for (int j = 0; j < 2; ++j) {
        int n = nb + wn + j * 16 + lc;
        float bi = bias[n];
#pragma unroll
        for (int i = 0; i < 2; ++i) {
            int m0 = mb + wm + i * 16 + lg * 4;
#pragma unroll
            for (int r = 0; r < 4; ++r)
                out[(size_t)(m0 + r) * DIM + n] = acc[i][j][r] + bi;
        }
    }
}

// ---------------------------------------------------------------------------
// Kernel B: single-pass attention, swapped QK^T, deferred normalization.
// r17: 4-wave blocks (256 thr) with internal k-tile split: wave (rh,th)
// handles rows rh*16..+16 over tile-half th (5 tiles) -> per-wave serial
// chain halves and waves/CU doubles at the SAME 51 KB LDS.  Cross-half
// combines: lsum/e0/e1 via small LDS arrays; PV partials merged through a
// scratch overlay in Pfull's dead region; rel-v/ctx done by waves 0-1.
// ---------------------------------------------------------------------------
__global__ __launch_bounds__(256) void attn_mfma(
    const ushort* __restrict__ qb, const ushort* __restrict__ kb,
    const ushort* __restrict__ vtb,
    const uint8_t* __restrict__ mtok, const uint8_t* __restrict__ mstm,
    const float* __restrict__ relk, const float* __restrict__ relv,
    const float* __restrict__ smk,  const float* __restrict__ smv,
    float* __restrict__ attn_out,
    ushort* __restrict__ ctxh, ushort* __restrict__ ctxl)
{
    __shared__ ushort qrel[32][72];
    __shared__ __align__(16) ushort Pfull[32][648];   // unnorm exp(score), bf16
    __shared__ ushort wbin[32][72];
    __shared__ float  linv[32];
    __shared__ float  ebuf[32];
    __shared__ float  pl[2][32], pe0[2][32], pe1[2][32];
    __shared__ uint64_t mlds[10];

    const int t    = threadIdx.x;
    const int lane = t & 63, w = t >> 6;
    const int rh = w & 1, th = w >> 1;              // row-half, tile-half
    const int swz  = ((blockIdx.x & 7) * 320) + (blockIdx.x >> 3);  // XCD-contig
    const int qt = swz % 20, bh = swz / 20;
    const int b = bh >> 4, h = bh & 15;
    const int qbase = qt * 32;
    const bool qstm = (qt >= 16);
    const size_t bhoff = (size_t)bh * (SS * HD);
    const int wq = rh * 16, lg = lane >> 4, lc = lane & 15;
    const int RR = qstm ? 16 : 32;
    const int NV = qstm ? 33 : 65;
    const float* tabk = qstm ? smk : relk;

    // waves 0,1 zero their row-half of wbin
    if (w < 2)
        for (int i = lane; i < 16 * 36; i += 64) {
            int r = i / 36, c = i - r * 36;
            *reinterpret_cast<uint32_t*>(&wbin[wq + r][c * 2]) = 0u;
        }

    // mask words: bit j of mlds[kt] covers key kt*64+j
    if (t < 10) {
        uint64_t m = 0;
        const int kb0 = t * 64;
#pragma unroll
        for (int j = 0; j < 64; ++j) {
            int kg = kb0 + j;
            uint8_t mb = (kg < STOK) ? mtok[b * STOK + kg] : mstm[b * STMN + kg - STOK];
            m |= ((uint64_t)(mb ? 1u : 0u)) << j;
        }
        mlds[t] = m;
    }

    // Q fragments (row = qbase+wq+lc): B-operand in swapped QK^T
    const int qrow = qbase + wq + lc;
    v8s aq0 = *reinterpret_cast<const v8s*>(&qb[bhoff + (size_t)qrow * HD + lg * 8]);
    v8s aq1 = *reinterpret_cast<const v8s*>(&qb[bhoff + (size_t)qrow * HD + 32 + lg * 8]);

    // qrel built by waves 0,1 (their own row-half)
    if (w < 2) {
        const int ndt = qstm ? 2 : 4;
        for (int dt = 0; dt < ndt; ++dt) {
            const float* rp = tabk + (size_t)(dt * 16 + lc) * HD;
            v8s bk0, bk1;
#pragma unroll
            for (int j = 0; j < 8; ++j) {
                bk0[j] = (short)f2b(rp[lg * 8 + j]);
                bk1[j] = (short)f2b(rp[32 + lg * 8 + j]);
            }
            v4f c4 = {0.f, 0.f, 0.f, 0.f};
            c4 = __builtin_amdgcn_mfma_f32_16x16x32_bf16(aq0, bk0, c4, 0, 0, 0);
            c4 = __builtin_amdgcn_mfma_f32_16x16x32_bf16(aq1, bk1, c4, 0, 0, 0);
#pragma unroll
            for (int r = 0; r < 4; ++r)
                qrel[wq + lg * 4 + r][dt * 16 + lc] = f2b(c4[r]);
        }
        const float* rp = tabk + (size_t)(NV - 1) * HD;
        float part = 0.f;
#pragma unroll
        for (int j = 0; j < 8; ++j) {
            part += b2f((ushort)aq0[j]) * rp[lg * 8 + j];
            part += b2f((ushort)aq1[j]) * rp[32 + lg * 8 + j];
        }
        part += __shfl_xor(part, 16);
        part += __shfl_xor(part, 32);
        if (lg == 0) qrel[wq + lc][NV - 1] = f2b(part);
    }
    __syncthreads();

    // per-lane scalars for this lane's single q-row
    const int gq = qbase + wq + lc;
    const float relLs = b2f(qrel[wq + lc][0]);
    const float relRs = b2f(qrel[wq + lc][2 * RR]);

    const int tile0 = qstm ? 8 : 0;
    const int tcnt = (10 - tile0) >> 1;
    const int tstart = tile0 + th * tcnt, tend = tstart + tcnt;

    float lsum1 = 0.f, e0 = 0.f, e1 = 0.f;
    v4f o[4];
#pragma unroll
    for (int dt = 0; dt < 4; ++dt) o[dt] = (v4f){0.f, 0.f, 0.f, 0.f};
    float* arow = attn_out + ((size_t)bh * SS + qbase) * SS;

    // ---- fused sweep over this wave's tile-half ----
    for (int kt = tstart; kt < tend; ++kt) {
        const ushort* kbase = kb + bhoff + (size_t)(kt * 64) * HD;
        const bool dorel = qstm || (kt < 8);
        const uint64_t mw = mlds[kt];
#pragma unroll
        for (int sub = 0; sub < 4; ++sub) {
            v8s bk0 = *reinterpret_cast<const v8s*>(&kbase[(sub * 16 + lc) * HD + lg * 8]);
            v8s bk1 = *reinterpret_cast<const v8s*>(&kbase[(sub * 16 + lc) * HD + 32 + lg * 8]);
            // SWAPPED: A = K-frag, B = Q-frag -> C[row=key][col=q]
            v4f c4 = {0.f, 0.f, 0.f, 0.f};
            c4 = __builtin_amdgcn_mfma_f32_16x16x32_bf16(bk0, aq0, c4, 0, 0, 0);
            c4 = __builtin_amdgcn_mfma_f32_16x16x32_bf16(bk1, aq1, c4, 0, 0, 0);
            const int kgb = kt * 64 + sub * 16 + lg * 4;   // lane's 4 consecutive keys
            float p4[4];
#pragma unroll
            for (int r = 0; r < 4; ++r) {
                int kg = kgb + r;
                int dlt = kg - gq;
                bool inband = dorel && (dlt > -RR) && (dlt < RR);
                float val = c4[r];
                if (dorel) {
                    float rv;
                    if (inband) rv = b2f(qrel[wq + lc][dlt + RR]);
                    else        rv = (dlt <= -RR) ? relLs : relRs;
                    val += rv;
                }
                if ((mw >> (sub * 16 + lg * 4 + r)) & 1) val = NEGINF;
                float p = __expf(val);              // UNNORMALIZED
                lsum1 += p;
                p4[r] = p;
                if (inband) wbin[wq + lc][dlt + RR] = f2b(p);
                else if (dorel) {
                    if (dlt <= -RR) e0 += p;
                    else            e1 += p;
                }
            }
            uint32_t lo = (uint32_t)f2b(p4[0]) | ((uint32_t)f2b(p4[1]) << 16);
            uint32_t hi = (uint32_t)f2b(p4[2]) | ((uint32_t)f2b(p4[3]) << 16);
            uint64_t pk64 = (uint64_t)lo | ((uint64_t)hi << 32);
            *reinterpret_cast<uint64_t*>(&Pfull[wq + lc][kgb]) = pk64;
        }
        // PV for this tile (A from own rows' Pfull, B = V^T frags)
        v8s ap0 = *reinterpret_cast<const v8s*>(&Pfull[wq + lc][kt * 64 + lg * 8]);
        v8s ap1 = *reinterpret_cast<const v8s*>(&Pfull[wq + lc][kt * 64 + 32 + lg * 8]);
        const ushort* vbase = vtb + bhoff + kt * 64;
#pragma unroll
        for (int dt = 0; dt < 4; ++dt) {
            v8s bv0 = *reinterpret_cast<const v8s*>(&vbase[(size_t)(dt * 16 + lc) * SS + lg * 8]);
            v8s bv1 = *reinterpret_cast<const v8s*>(&vbase[(size_t)(dt * 16 + lc) * SS + 32 + lg * 8]);
            o[dt] = __builtin_amdgcn_mfma_f32_16x16x32_bf16(ap0, bv0, o[dt], 0, 0, 0);
            o[dt] = __builtin_amdgcn_mfma_f32_16x16x32_bf16(ap1, bv1, o[dt], 0, 0, 0);
        }
    }

    // per-lane reduces over lg groups -> per-row partials for (rh, th)
    {
        float s = lsum1;
        s += __shfl_xor(s, 16); s += __shfl_xor(s, 32);
        float e0s = e0;
        e0s += __shfl_xor(e0s, 16); e0s += __shfl_xor(e0s, 32);
        float e1s = e1;
        e1s += __shfl_xor(e1s, 16); e1s += __shfl_xor(e1s, 32);
        if (lg == 0) {
            pl[th][wq + lc]  = s;
            pe0[th][wq + lc] = e0s;
            pe1[th][wq + lc] = e1s;
        }
    }
    __syncthreads();

    // combine halves (one thread per row)
    if (t < 32) {
        int row = t;
        float ls = pl[0][row] + pl[1][row];
        linv[row] = 1.f / ls;
        float e0s = pe0[0][row] + pe0[1][row];
        float e1s = pe1[0][row] + pe1[1][row];
        ebuf[row] = e1s;
        wbin[row][0] = f2b(e0s);
        if (qstm) wbin[row][32] = f2b(e1s);
    }
    __syncthreads();

    // ---- row-contiguous normalize+write of attn (nt stores); 8 rows/wave ----
#pragma unroll
    for (int rr = 0; rr < 2; ++rr) {
        int row = w * 8 + rr * 4 + lg;
        float iv = linv[row];
        float* rowp = arow + (size_t)row * SS;
        if (qstm) {
            v4f z = (v4f){0.f, 0.f, 0.f, 0.f};
#pragma unroll
            for (int kt = 0; kt < 8; ++kt)
                __builtin_nontemporal_store(z,
                    reinterpret_cast<v4f*>(&rowp[kt * 64 + lc * 4]));
#pragma unroll
            for (int kt = 8; kt < 10; ++kt) {
                ushort4 pk = *reinterpret_cast<ushort4*>(&Pfull[row][kt * 64 + lc * 4]);
                v4f pv4;
                pv4[0] = b2f(pk.x) * iv;
                pv4[1] = b2f(pk.y) * iv;
                pv4[2] = b2f(pk.z) * iv;
                pv4[3] = b2f(pk.w) * iv;
                __builtin_nontemporal_store(pv4,
                    reinterpret_cast<v4f*>(&rowp[kt * 64 + lc * 4]));
            }
        } else {
#pragma unroll
            for (int kt = 0; kt < 10; ++kt) {
                ushort4 pk = *reinterpret_cast<ushort4*>(&Pfull[row][kt * 64 + lc * 4]);
                v4f pv4;
                pv4[0] = b2f(pk.x) * iv;
                pv4[1] = b2f(pk.y) * iv;
                pv4[2] = b2f(pk.z) * iv;
                pv4[3] = b2f(pk.w) * iv;
                __builtin_nontemporal_store(pv4,
                    reinterpret_cast<v4f*>(&rowp[kt * 64 + lc * 4]));
            }
        }
    }
    __syncthreads();

    // ---- overlay merge of PV partials + rel-v staging ----
    // overlay (f32 [32][64]) lives in Pfull's dead region (ushort idx 16384+)
    float* ob = reinterpret_cast<float*>(&Pfull[0][0] + 16384);
    if (w >= 2) {
#pragma unroll
        for (int dt = 0; dt < 4; ++dt)
#pragma unroll
            for (int r = 0; r < 4; ++r)
                ob[(wq + lg * 4 + r) * 64 + dt * 16 + lc] = o[dt][r];
    }
    {   // rel-v table into Pfull[0..4607] (ushort idx), all threads
        ushort* Rv = &Pfull[0][0];
        const float* tabv = qstm ? smv : relv;
        for (int idx = t; idx < 64 * 64; idx += 256) {
            int d = idx >> 6, v = idx & 63;
            float f = (v < NV) ? tabv[(size_t)v * HD + d] : 0.f;
            Rv[d * 72 + v] = f2b(f);
        }
    }
    __syncthreads();

    if (w < 2) {
        // merge tile-half partials
#pragma unroll
        for (int dt = 0; dt < 4; ++dt)
#pragma unroll
            for (int r = 0; r < 4; ++r)
                o[dt][r] += ob[(wq + lg * 4 + r) * 64 + dt * 16 + lc];

        const ushort* Rv = &Pfull[0][0];
        v8s aw0 = *reinterpret_cast<const v8s*>(&wbin[wq + lc][lg * 8]);
        v8s aw1 = *reinterpret_cast<const v8s*>(&wbin[wq + lc][32 + lg * 8]);
#pragma unroll
        for (int dt = 0; dt < 4; ++dt) {
            v8s bv0 = *reinterpret_cast<const v8s*>(&Rv[(dt * 16 + lc) * 72 + lg * 8]);
            v8s bv1 = *reinterpret_cast<const v8s*>(&Rv[(dt * 16 + lc) * 72 + 32 + lg * 8]);
            o[dt] = __builtin_amdgcn_mfma_f32_16x16x32_bf16(aw0, bv0, o[dt], 0, 0, 0);
            o[dt] = __builtin_amdgcn_mfma_f32_16x16x32_bf16(aw1, bv1, o[dt], 0, 0, 0);
        }
        if (!qstm) {   // rank-1 fixup for bin v=64
#pragma unroll
            for (int r = 0; r < 4; ++r) {
                float e1r = ebuf[wq + lg * 4 + r];
#pragma unroll
                for (int dt = 0; dt < 4; ++dt)
                    o[dt][r] += e1r * relv[(size_t)64 * HD + dt * 16 + lc];
            }
        }

        // normalize o and write ctx as bf16 hi/lo [b][s][h*64+d]
        float invr[4];
#pragma unroll
        for (int r = 0; r < 4; ++r) invr[r] = linv[wq + lg * 4 + r];
#pragma unroll
        for (int dt = 0; dt < 4; ++dt)
#pragma unroll
            for (int r = 0; r < 4; ++r) {
                int gq2 = qbase + wq + lg * 4 + r;
                size_t idx = ((size_t)b * SS + gq2) * DIM + h * HD + dt * 16 + lc;
                float v = o[dt][r] * invr[r];
                ushort hi = f2b(v);
                ctxh[idx] = hi;
                ctxl[idx] = f2b(v - b2f(hi));
            }
    }
}

// ---------------------------------------------------------------------------
extern "C" void kernel_launch(void* const* d_in, const int* in_sizes, int n_in,
                              void* d_out, int out_size, void* d_ws, size_t ws_size,
                              hipStream_t stream)
{
    const float*   stok  = (const float*)d_in[0];
    const float*   stm   = (const float*)d_in[1];
    const uint8_t* mtok  = (const uint8_t*)d_in[2];
    const uint8_t* mstm  = (const uint8_t*)d_in[3];
    const float*   qkv_w = (const float*)d_in[4];
    const float*   qkv_b = (const float*)d_in[5];
    const float*   out_w = (const float*)d_in[6];
    const float*   out_b = (const float*)d_in[7];
    const float*   relk  = (const float*)d_in[8];
    const float*   relv  = (const float*)d_in[9];
    const float*   smk   = (const float*)d_in[10];
    const float*   smv   = (const float*)d_in[11];

    float* out_final = (float*)d_out;
    float* out_attn  = out_final + (size_t)BB * SS * DIM;

    const size_t SZ = (size_t)BB * HH * SS * HD;           // 5,242,880
    ushort* qb16 = (ushort*)d_ws;
    ushort* kb16 = qb16 + SZ;
    ushort* vt16 = kb16 + SZ;
    ushort* xb16 = vt16 + SZ;                              // 5,242,880 ushorts
    ushort* wb16 = xb16 + SZ;                              // 3,145,728 ushorts
    ushort* ctxh = wb16 + (size_t)3 * DIM * DIM;
    ushort* ctxl = ctxh + SZ;
    ushort* woh  = ctxl + SZ;                              // 1,048,576 ushorts
    ushort* wol  = woh + (size_t)DIM * DIM;

    cvt_bf16<<<dim3(9216), dim3(256), 0, stream>>>(stok, stm, qkv_w, out_w,
                                                   xb16, wb16, woh, wol);
    gemm_qkv_mfma<<<dim3(1920), dim3(256), 0, stream>>>(xb16, wb16, qkv_b, qb16, kb16, vt16);
    attn_mfma<<<dim3(2560), dim3(256), 0, stream>>>(qb16, kb16, vt16, mtok, mstm,
                                                    relk, relv, smk, smv, out_attn, ctxh, ctxl);
    gemm_out_mfma<<<dim3(1280), dim3(256), 0, stream>>>(ctxh, ctxl, woh, wol, out_b, out_final);
}